// Round 12
// baseline (204.203 us; speedup 1.0000x reference)
//
#include <hip/hip_runtime.h>
#include <hip/hip_bf16.h>

// Problem: B=8, S=1024, EMBED=1024, DK=DV=512, M=64. Inputs/outputs f32.
// Identity: landmark selection is a segment permutation P of k, so
// kernel_1 = K3 P^T, pinv(kernel_2) = P pinv(K3), and
// out = K3 K3+ K3 v = K3 v == softmax(q k^T) v  (standard attention).
// Softmax is computed UNNORMALIZED (no max-shift: logits ~N(0,1), max < 6,
// exp < 400, safe): scores stores exp(S) as bf16; pv accumulates the row
// denominator from the SAME bf16 fragments it feeds the MFMA (quad-lanes of
// a row collectively cover the full k-slice each iter) and divides at the end.
#define SS   1024
#define DKK  512

typedef __hip_bfloat16 bf16;
typedef __attribute__((ext_vector_type(8))) short s16x8;            // 8 x bf16
typedef __attribute__((ext_vector_type(8))) unsigned short u16x8;
typedef __attribute__((ext_vector_type(4))) float f32x4;

// ---- ws layout (byte offsets), 76 MiB ----
// expS 16 MiB at 0; W(z) bf16 1 MiB at 48+z MiB; q 52 MiB; k 60 MiB;
// vT 68 MiB.
#define WS_W(z)  ((48ull << 20) + ((size_t)(z) << 20))
#define WS_Q     (52ull << 20)
#define WS_K     (60ull << 20)
#define WS_VT    (68ull << 20)
#define WS_LG    (0ull)

__device__ __forceinline__ void async_ld16(const void* g, void* s) {
  __builtin_amdgcn_global_load_lds(
      (const __attribute__((address_space(1))) void*)g,
      (__attribute__((address_space(3))) void*)s, 16, 0, 0);
}

__device__ __forceinline__ unsigned short f2bfu(float f) {
  return __builtin_bit_cast(unsigned short, __float2bfloat16(f));
}
__device__ __forceinline__ float bfu2f(unsigned short u) {
  unsigned int i = ((unsigned int)u) << 16;
  return __builtin_bit_cast(float, i);
}

#define FENCE() __builtin_amdgcn_sched_barrier(0)

// Convert the 3 weight tensors (512K elems each) f32 -> bf16 into ws.
__global__ __launch_bounds__(256)
void convert_w(const float* __restrict__ w0, const float* __restrict__ w1,
               const float* __restrict__ w2, char* __restrict__ ws)
{
  const int bx = blockIdx.x;
  const int z = bx >> 8, local = bx & 255;
  const float* src = (z == 0) ? w0 : (z == 1) ? w1 : w2;
  unsigned short* dst = (unsigned short*)(ws + WS_W(z));
  const int i = local * 2048 + threadIdx.x * 8;
  const float4* s = (const float4*)(src + i);
  float4 a = s[0], b = s[1];
  ushort4 o0, o1;
  o0.x = f2bfu(a.x); o0.y = f2bfu(a.y); o0.z = f2bfu(a.z); o0.w = f2bfu(a.w);
  o1.x = f2bfu(b.x); o1.y = f2bfu(b.y); o1.z = f2bfu(b.z); o1.w = f2bfu(b.w);
  ((ushort4*)(dst + i))[0] = o0;
  ((ushort4*)(dst + i))[1] = o1;
}

// ---------- bf16 x bf16 core ----------
// C[BM x 128] = A[BM x K] * B[128 x K]^T, both K-contiguous bf16.
// LDS via global_load_lds w=16; LDS[row][slot] holds chunk (slot ^ (row&7)).
// 4 waves, wave tile (BM/2) x 64, acc[mi*4+ni] with MI = BM/32.
template<int BM, int K, int LDA, int LDB>
__device__ __forceinline__ void gemm_core(const bf16* __restrict__ A,
                                          const bf16* __restrict__ Bw,
                                          int bm, int bn,
                                          short* As, short* Bs, f32x4* acc)
{
  constexpr int MI = BM / 32;
  constexpr int AR = BM / 4;
  const int tid  = threadIdx.x;
  const int lane = tid & 63;
  const int wave = tid >> 6;
  const int l8   = lane >> 3;
  const int kch  = ((lane & 7) ^ l8) * 8;
  const bf16* ag = A  + (size_t)(bm * BM + wave * AR + l8) * LDA + kch;
  const bf16* bg = Bw + (size_t)(bn * 128 + wave * 32 + l8) * LDB + kch;
  short* AsW = As + wave * AR * 64;
  short* BsW = Bs + wave * 32 * 64;
  const int waveM = wave >> 1, waveN = wave & 1;
  const int l16  = lane & 15;
  const int quad = lane >> 4;
  const int xr   = l16 & 7;

  #pragma unroll
  for (int t = 0; t < MI * 4; ++t)
    #pragma unroll
    for (int r = 0; r < 4; ++r) acc[t][r] = 0.0f;

  for (int kt = 0; kt < K / 64; ++kt) {
    #pragma unroll
    for (int j = 0; j < AR / 8; ++j) async_ld16(ag + (size_t)j * 8 * LDA, AsW + j * 8 * 64);
    #pragma unroll
    for (int j = 0; j < 4; ++j)      async_ld16(bg + (size_t)j * 8 * LDB, BsW + j * 8 * 64);
    ag += 64; bg += 64;
    __syncthreads();
    #pragma unroll
    for (int ks = 0; ks < 2; ++ks) {
      s16x8 af[MI], bfv[4];
      #pragma unroll
      for (int mi = 0; mi < MI; ++mi) {
        const int row  = waveM * (BM / 2) + mi * 16 + l16;
        const int slot = (ks * 4 + quad) ^ xr;
        af[mi] = *(const s16x8*)&As[row * 64 + slot * 8];
      }
      #pragma unroll
      for (int ni = 0; ni < 4; ++ni) {
        const int row  = waveN * 64 + ni * 16 + l16;
        const int slot = (ks * 4 + quad) ^ xr;
        bfv[ni] = *(const s16x8*)&Bs[row * 64 + slot * 8];
      }
      #pragma unroll
      for (int mi = 0; mi < MI; ++mi)
        #pragma unroll
        for (int ni = 0; ni < 4; ++ni)
          acc[mi * 4 + ni] = __builtin_amdgcn_mfma_f32_16x16x32_bf16(
              af[mi], bfv[ni], acc[mi * 4 + ni], 0, 0, 0);
    }
    __syncthreads();
  }
}

// ---------- f32-A x bf16-B core for proj: BM=64, BN=256 (R5 version) ----------
// A f32 prefetched into registers one K-step ahead (T14 async-STAGE split);
// raw s_barrier + counted s_waitcnt vmcnt(4) keeps the 4 in-flight A loads
// alive across the barrier. B bf16 on the async global_load_lds path.
// Wave tile 32x128. Measured 57-64 us across runs.
template<int K, int LDA, int LDB>
__device__ __forceinline__ void gemm_core_f32a(const float* __restrict__ A,
                                               const bf16* __restrict__ Bw,
                                               int bm, int bn,
                                               short* As, short* Bs, f32x4* acc)
{
  const int tid  = threadIdx.x;
  const int lane = tid & 63;
  const int wave = tid >> 6;
  const int l8   = lane >> 3;
  const int kch  = ((lane & 7) ^ l8) * 8;
  const bf16* bg = Bw + (size_t)(bn * 256 + wave * 64 + l8) * LDB + kch;
  short* BsW = Bs + wave * 64 * 64;
  const int arow = tid >> 3;
  const int ag8  = tid & 7;
  const int slotA = (ag8 ^ (arow & 7)) * 8;
  const float* ag = A + (size_t)(bm * 64 + arow) * LDA + ag8 * 8;
  const int waveM = wave >> 1, waveN = wave & 1;
  const int l16  = lane & 15;
  const int quad = lane >> 4;
  const int xr   = l16 & 7;

  #pragma unroll
  for (int t = 0; t < 16; ++t)
    #pragma unroll
    for (int r = 0; r < 4; ++r) acc[t][r] = 0.0f;

  // prologue: A regs for kt=0
  float4 a0 = ((const float4*)ag)[0];
  float4 b0 = ((const float4*)ag)[1];
  float4 a1 = ((const float4*)(ag + (size_t)32 * LDA))[0];
  float4 b1 = ((const float4*)(ag + (size_t)32 * LDA))[1];
  ag += 64;

  for (int kt = 0; kt < K / 64; ++kt) {
    // (1) issue B DMA loads (must be the 8 oldest vm ops at the waitcnt)
    #pragma unroll
    for (int j = 0; j < 8; ++j) async_ld16(bg + (size_t)j * 8 * LDB, BsW + j * 8 * 64);
    bg += 64;
    FENCE();
    // (2) cvt current A regs -> swizzled LDS (compiler waits on their loads)
    {
      u16x8 v;
      v[0] = f2bfu(a0.x); v[1] = f2bfu(a0.y); v[2] = f2bfu(a0.z); v[3] = f2bfu(a0.w);
      v[4] = f2bfu(b0.x); v[5] = f2bfu(b0.y); v[6] = f2bfu(b0.z); v[7] = f2bfu(b0.w);
      *(u16x8*)&As[arow * 64 + slotA] = v;
      v[0] = f2bfu(a1.x); v[1] = f2bfu(a1.y); v[2] = f2bfu(a1.z); v[3] = f2bfu(a1.w);
      v[4] = f2bfu(b1.x); v[5] = f2bfu(b1.y); v[6] = f2bfu(b1.z); v[7] = f2bfu(b1.w);
      *(u16x8*)&As[(32 + arow) * 64 + slotA] = v;
    }
    // (3) issue next-iteration A loads (stay in flight across the barrier);
    //     last iter re-reads the current chunk to keep vmcnt count constant
    //     and stay in-bounds.
    const float* agn = (kt == K / 64 - 1) ? (ag - 64) : ag;
    float4 na0 = ((const float4*)agn)[0];
    float4 nb0 = ((const float4*)agn)[1];
    float4 na1 = ((const float4*)(agn + (size_t)32 * LDA))[0];
    float4 nb1 = ((const float4*)(agn + (size_t)32 * LDA))[1];
    ag += 64;
    FENCE();
    // B DMAs (8) done; A prefetch (4) may remain in flight; LDS writes done.
    asm volatile("s_waitcnt vmcnt(4) lgkmcnt(0)" ::: "memory");
    __builtin_amdgcn_s_barrier();
    FENCE();
    #pragma unroll
    for (int ks = 0; ks < 2; ++ks) {
      s16x8 af[2], bfv[8];
      #pragma unroll
      for (int mi = 0; mi < 2; ++mi) {
        const int row  = waveM * 32 + mi * 16 + l16;
        const int slot = (ks * 4 + quad) ^ xr;
        af[mi] = *(const s16x8*)&As[row * 64 + slot * 8];
      }
      #pragma unroll
      for (int ni = 0; ni < 8; ++ni) {
        const int row  = waveN * 128 + ni * 16 + l16;
        const int slot = (ks * 4 + quad) ^ xr;
        bfv[ni] = *(const s16x8*)&Bs[row * 64 + slot * 8];
      }
      #pragma unroll
      for (int mi = 0; mi < 2; ++mi)
        #pragma unroll
        for (int ni = 0; ni < 8; ++ni)
          acc[mi * 8 + ni] = __builtin_amdgcn_mfma_f32_16x16x32_bf16(
              af[mi], bfv[ni], acc[mi * 8 + ni], 0, 0, 0);
    }
    FENCE();
    asm volatile("s_waitcnt lgkmcnt(0)" ::: "memory");
    __builtin_amdgcn_s_barrier();
    FENCE();
    a0 = na0; b0 = nb0; a1 = na1; b1 = nb1;
  }
}

// z=0: q = (Xq Wq^T + bq) * 512^-0.5 ; z=1: k = Xk Wk^T + bk ;
// z=2: vT[b][d][s] = (Xv Wv^T + bv)^T.
// Flat 768-block grid; the two bn-siblings of each (bm,z) panel get linear
// ids differing by 8 -> same XCD -> A panel shared in that XCD's L2.
__global__ __launch_bounds__(256, 3)
void proj_kernel(const float* __restrict__ Xq, const float* __restrict__ Xk,
                 const float* __restrict__ Xv, const bf16* __restrict__ W0,
                 const float* __restrict__ bq, const float* __restrict__ bk,
                 const float* __restrict__ bv,
                 bf16* __restrict__ qo, bf16* __restrict__ ko,
                 bf16* __restrict__ vT, float qscale)
{
  __shared__ __align__(16) short As[64 * 64];
  __shared__ __align__(16) short Bs[256 * 64];
  const int id   = blockIdx.x;
  const int xcd  = id & 7;
  const int s    = id >> 3;            // 0..95
  const int bn   = s & 1;
  const int pair = (s >> 1) * 8 + xcd; // 0..383 unique
  const int bm   = pair & 127;
  const int z    = pair >> 7;          // 0..2
  const float* A  = (z == 0) ? Xq : (z == 1) ? Xk : Xv;
  const bf16*  Bw = W0 + ((size_t)z << 19);
  const float* bias = (z == 0) ? bq : (z == 1) ? bk : bv;
  f32x4 acc[16];
  gemm_core_f32a<1024, 1024, 1024>(A, Bw, bm, bn, As, Bs, acc);

  const int lane = threadIdx.x & 63;
  const int wave = threadIdx.x >> 6;
  const int waveM = wave >> 1, waveN = wave & 1;
  const int l16 = lane & 15, quad = lane >> 4;
  const int row0 = bm * 64 + waveM * 32;
  const int col0 = bn * 256 + waveN * 128;
  const float sc = (z == 0) ? qscale : 1.0f;
  bf16* C = (z == 0) ? qo : ko;
  #pragma unroll
  for (int ni = 0; ni < 8; ++ni) {
    const int col = col0 + ni * 16 + l16;
    const float bb = bias[col];
    #pragma unroll
    for (int mi = 0; mi < 2; ++mi)
      #pragma unroll
      for (int r = 0; r < 4; ++r) {
        const int row = row0 + mi * 16 + quad * 4 + r;
        const float v = acc[mi * 8 + ni][r] + bb;
        if (z == 2)
          vT[((size_t)(row >> 10) * DKK + col) * SS + (row & (SS - 1))] =
              __float2bfloat16(v);
        else
          C[(size_t)row * DKK + col] = __float2bfloat16(v * sc);
      }
  }
}

// expS[b][s][t] = exp(q[b][s].k[b][t]); 128x128 tiles (more MFMA work per
// barrier-pair than the 64-row tile), GEMM + exp in epilogue.
// Flat grid 512 (2/CU): z = id&7 (q+k for one z = 2 MiB, L2-resident per
// XCD), s = id>>3: bm = s&7, bn = s>>3.
__global__ __launch_bounds__(256, 3)
void scores_kernel(const bf16* __restrict__ q, const bf16* __restrict__ k,
                   bf16* __restrict__ lgB)
{
  __shared__ __align__(16) short As[128 * 64];
  __shared__ __align__(16) short Bs[128 * 64];
  const int id = blockIdx.x;
  const int z  = id & 7;
  const int s  = id >> 3;          // 0..63
  const int bm = s & 7;
  const int bn = s >> 3;           // 0..7
  f32x4 acc[16];
  gemm_core<128, 512, 512, 512>(q + (size_t)z * SS * DKK, k + (size_t)z * SS * DKK,
                                bm, bn, As, Bs, acc);

  const int lane = threadIdx.x & 63;
  const int wave = threadIdx.x >> 6;
  const int waveM = wave >> 1, waveN = wave & 1;
  const int l16 = lane & 15, quad = lane >> 4;
  const int row0 = bm * 128 + waveM * 64;
  const int col0 = bn * 128 + waveN * 64;
  bf16* C = lgB + (size_t)z * SS * SS;
  #pragma unroll
  for (int ni = 0; ni < 4; ++ni) {
    const int col = col0 + ni * 16 + l16;
    #pragma unroll
    for (int mi = 0; mi < 4; ++mi)
      #pragma unroll
      for (int r = 0; r < 4; ++r) {
        const int row = row0 + mi * 16 + quad * 4 + r;
        C[(size_t)row * SS + col] = __float2bfloat16(__expf(acc[mi * 4 + ni][r]));
      }
  }
}

// out[b][s][d] = (P . vT) / rowsum(P), P = expS bf16; f32 out.
// Pure all-DMA GEMM: A and B both on the async global_load_lds path.
// The denominator is accumulated during the MFMA phase: the 4 quad-lanes of
// each row read that row's full 64-wide k-slice per iteration (slot XOR is a
// bijection), so summing af fragments per lane + shfl_xor(16|32) at the end
// gives exact row sums of the bf16 P values fed to the MFMA.
// Flat grid 512 (2/CU): z = id&7, s = id>>3: bm = s&15, bn = s>>4 (0..3).
__global__ __launch_bounds__(256, 4)
void pv_kernel(const bf16* __restrict__ P, const bf16* __restrict__ vT,
               float* __restrict__ out)
{
  __shared__ __align__(16) short As[64 * 64];
  __shared__ __align__(16) short Bs[128 * 64];
  __shared__ float Ls[64];
  const int id = blockIdx.x;
  const int z  = id & 7;
  const int sx = id >> 3;          // 0..63
  const int bm = sx & 15;
  const int bn = sx >> 4;          // 0..3
  const bf16* A  = P  + (size_t)z * SS * SS;
  const bf16* Bw = vT + (size_t)z * DKK * SS;

  const int tid  = threadIdx.x;
  const int lane = tid & 63;
  const int wave = tid >> 6;
  const int l8   = lane >> 3;
  const int kch  = ((lane & 7) ^ l8) * 8;
  const bf16* ag = A  + (size_t)(bm * 64 + wave * 16 + l8) * 1024 + kch;
  const bf16* bg = Bw + (size_t)(bn * 128 + wave * 32 + l8) * 1024 + kch;
  short* AsW = As + wave * 16 * 64;
  short* BsW = Bs + wave * 32 * 64;
  const int waveM = wave >> 1, waveN = wave & 1;
  const int l16  = lane & 15;
  const int quad = lane >> 4;
  const int xr   = l16 & 7;

  f32x4 acc[8];
  #pragma unroll
  for (int t = 0; t < 8; ++t)
    #pragma unroll
    for (int r = 0; r < 4; ++r) acc[t][r] = 0.0f;
  float es0 = 0.0f, es1 = 0.0f;   // row sums for rows waveM*32 + {l16, 16+l16}

  for (int kt = 0; kt < 16; ++kt) {
    #pragma unroll
    for (int j = 0; j < 2; ++j) async_ld16(ag + (size_t)j * 8 * 1024, AsW + j * 8 * 64);
    #pragma unroll
    for (int j = 0; j < 4; ++j) async_ld16(bg + (size_t)j * 8 * 1024, BsW + j * 8 * 64);
    ag += 64; bg += 64;
    __syncthreads();
    #pragma unroll
    for (int ks = 0; ks < 2; ++ks) {
      s16x8 af[2], bfv[4];
      #pragma unroll
      for (int mi = 0; mi < 2; ++mi) {
        const int row  = waveM * 32 + mi * 16 + l16;
        const int slot = (ks * 4 + quad) ^ xr;
        af[mi] = *(const s16x8*)&As[row * 64 + slot * 8];
      }
      // denominator accumulation from the same fragments (VALU, co-issues
      // with the MFMA pipe)
      {
        const u16x8 u0 = __builtin_bit_cast(u16x8, af[0]);
        const u16x8 u1 = __builtin_bit_cast(u16x8, af[1]);
        #pragma unroll
        for (int e = 0; e < 8; ++e) {
          es0 += bfu2f((unsigned short)u0[e]);
          es1 += bfu2f((unsigned short)u1[e]);
        }
      }
      #pragma unroll
      for (int ni = 0; ni < 4; ++ni) {
        const int row  = waveN * 64 + ni * 16 + l16;
        const int slot = (ks * 4 + quad) ^ xr;
        bfv[ni] = *(const s16x8*)&Bs[row * 64 + slot * 8];
      }
      #pragma unroll
      for (int mi = 0; mi < 2; ++mi)
        #pragma unroll
        for (int ni = 0; ni < 4; ++ni)
          acc[mi * 4 + ni] = __builtin_amdgcn_mfma_f32_16x16x32_bf16(
              af[mi], bfv[ni], acc[mi * 4 + ni], 0, 0, 0);
    }
    __syncthreads();
  }

  // combine across the 4 quad-lanes of each row (lanes differ in bits 4,5)
  es0 += __shfl_xor(es0, 16); es0 += __shfl_xor(es0, 32);
  es1 += __shfl_xor(es1, 16); es1 += __shfl_xor(es1, 32);
  if (waveN == 0 && quad == 0) {
    Ls[waveM * 32 + l16]      = 1.0f / es0;
    Ls[waveM * 32 + 16 + l16] = 1.0f / es1;
  }
  __syncthreads();

  const int col0 = bn * 128 + waveN * 64;
  float* C = out + (size_t)z * SS * DKK;
  #pragma unroll
  for (int mi = 0; mi < 2; ++mi)
    #pragma unroll
    for (int r = 0; r < 4; ++r) {
      const int rl  = waveM * 32 + mi * 16 + quad * 4 + r;
      const float inv = Ls[rl];
      const int row = bm * 64 + rl;
      #pragma unroll
      for (int ni = 0; ni < 4; ++ni) {
        const int col = col0 + ni * 16 + l16;
        C[(size_t)row * DKK + col] = acc[mi * 4 + ni][r] * inv;
      }
    }
}

extern "C" void kernel_launch(void* const* d_in, const int* in_sizes, int n_in,
                              void* d_out, int out_size, void* d_ws, size_t ws_size,
                              hipStream_t stream)
{
  char* ws = (char*)d_ws;
  bf16*  W0   = (bf16*)(ws + WS_W(0));
  bf16*  q    = (bf16*)(ws + WS_Q);
  bf16*  kk   = (bf16*)(ws + WS_K);
  bf16*  vT   = (bf16*)(ws + WS_VT);
  bf16*  lgB  = (bf16*)(ws + WS_LG);

  const float qscale = 0.044194173824159216f;  // 512^-0.5

  dim3 blk(256, 1, 1);
  // d_in order: qin,kin,vin,Wq,bq,Wk,bk,Wv,bv (all f32)
  hipLaunchKernelGGL(convert_w, dim3(768), blk, 0, stream,
                     (const float*)d_in[3], (const float*)d_in[5],
                     (const float*)d_in[7], ws);
  hipLaunchKernelGGL(proj_kernel, dim3(768, 1, 1), blk, 0, stream,
                     (const float*)d_in[0], (const float*)d_in[1],
                     (const float*)d_in[2], W0,
                     (const float*)d_in[4], (const float*)d_in[6],
                     (const float*)d_in[8], q, kk, vT, qscale);
  hipLaunchKernelGGL(scores_kernel, dim3(512, 1, 1), blk, 0, stream,
                     q, kk, lgB);
  hipLaunchKernelGGL(pv_kernel, dim3(512, 1, 1), blk, 0, stream,
                     lgB, vT, (float*)d_out);
}

// Round 13
// 201.779 us; speedup vs baseline: 1.0120x; 1.0120x over previous
//
#include <hip/hip_runtime.h>
#include <hip/hip_bf16.h>

// Problem: B=8, S=1024, EMBED=1024, DK=DV=512, M=64. Inputs/outputs f32.
// Identity: landmark selection is a segment permutation P of k, so
// kernel_1 = K3 P^T, pinv(kernel_2) = P pinv(K3), and
// out = K3 K3+ K3 v = K3 v == softmax(q k^T) v  (standard attention).
// Softmax is computed UNNORMALIZED (no max-shift: logits ~N(0,1), max < 6,
// exp < 400, safe): scores stores exp(S) as bf16; pv accumulates the row
// denominator from the SAME bf16 fragments it feeds the MFMA (quad-lanes of
// a row collectively cover the full k-slice each iter) and divides at the end.
#define SS   1024
#define DKK  512

typedef __hip_bfloat16 bf16;
typedef __attribute__((ext_vector_type(8))) short s16x8;            // 8 x bf16
typedef __attribute__((ext_vector_type(8))) unsigned short u16x8;
typedef __attribute__((ext_vector_type(4))) float f32x4;

// ---- ws layout (byte offsets), 76 MiB ----
// expS 16 MiB at 0; W(z) bf16 1 MiB at 48+z MiB; q 52 MiB; k 60 MiB;
// vT 68 MiB.
#define WS_W(z)  ((48ull << 20) + ((size_t)(z) << 20))
#define WS_Q     (52ull << 20)
#define WS_K     (60ull << 20)
#define WS_VT    (68ull << 20)
#define WS_LG    (0ull)

__device__ __forceinline__ void async_ld16(const void* g, void* s) {
  __builtin_amdgcn_global_load_lds(
      (const __attribute__((address_space(1))) void*)g,
      (__attribute__((address_space(3))) void*)s, 16, 0, 0);
}

__device__ __forceinline__ unsigned short f2bfu(float f) {
  return __builtin_bit_cast(unsigned short, __float2bfloat16(f));
}
__device__ __forceinline__ float bfu2f(unsigned short u) {
  unsigned int i = ((unsigned int)u) << 16;
  return __builtin_bit_cast(float, i);
}

#define FENCE() __builtin_amdgcn_sched_barrier(0)

// Convert the 3 weight tensors (512K elems each) f32 -> bf16 into ws.
__global__ __launch_bounds__(256)
void convert_w(const float* __restrict__ w0, const float* __restrict__ w1,
               const float* __restrict__ w2, char* __restrict__ ws)
{
  const int bx = blockIdx.x;
  const int z = bx >> 8, local = bx & 255;
  const float* src = (z == 0) ? w0 : (z == 1) ? w1 : w2;
  unsigned short* dst = (unsigned short*)(ws + WS_W(z));
  const int i = local * 2048 + threadIdx.x * 8;
  const float4* s = (const float4*)(src + i);
  float4 a = s[0], b = s[1];
  ushort4 o0, o1;
  o0.x = f2bfu(a.x); o0.y = f2bfu(a.y); o0.z = f2bfu(a.z); o0.w = f2bfu(a.w);
  o1.x = f2bfu(b.x); o1.y = f2bfu(b.y); o1.z = f2bfu(b.z); o1.w = f2bfu(b.w);
  ((ushort4*)(dst + i))[0] = o0;
  ((ushort4*)(dst + i))[1] = o1;
}

// ---------- f32-A x bf16-B core for proj: BM=64, BN=256 (R5 version) ----------
// A f32 prefetched into registers one K-step ahead (T14 async-STAGE split);
// raw s_barrier + counted s_waitcnt vmcnt(4) keeps the 4 in-flight A loads
// alive across the barrier. B bf16 on the async global_load_lds path.
// Wave tile 32x128. Measured 57-65 us across runs (noise band ~±3 us).
template<int K, int LDA, int LDB>
__device__ __forceinline__ void gemm_core_f32a(const float* __restrict__ A,
                                               const bf16* __restrict__ Bw,
                                               int bm, int bn,
                                               short* As, short* Bs, f32x4* acc)
{
  const int tid  = threadIdx.x;
  const int lane = tid & 63;
  const int wave = tid >> 6;
  const int l8   = lane >> 3;
  const int kch  = ((lane & 7) ^ l8) * 8;
  const bf16* bg = Bw + (size_t)(bn * 256 + wave * 64 + l8) * LDB + kch;
  short* BsW = Bs + wave * 64 * 64;
  const int arow = tid >> 3;
  const int ag8  = tid & 7;
  const int slotA = (ag8 ^ (arow & 7)) * 8;
  const float* ag = A + (size_t)(bm * 64 + arow) * LDA + ag8 * 8;
  const int waveM = wave >> 1, waveN = wave & 1;
  const int l16  = lane & 15;
  const int quad = lane >> 4;
  const int xr   = l16 & 7;

  #pragma unroll
  for (int t = 0; t < 16; ++t)
    #pragma unroll
    for (int r = 0; r < 4; ++r) acc[t][r] = 0.0f;

  // prologue: A regs for kt=0
  float4 a0 = ((const float4*)ag)[0];
  float4 b0 = ((const float4*)ag)[1];
  float4 a1 = ((const float4*)(ag + (size_t)32 * LDA))[0];
  float4 b1 = ((const float4*)(ag + (size_t)32 * LDA))[1];
  ag += 64;

  for (int kt = 0; kt < K / 64; ++kt) {
    // (1) issue B DMA loads (must be the 8 oldest vm ops at the waitcnt)
    #pragma unroll
    for (int j = 0; j < 8; ++j) async_ld16(bg + (size_t)j * 8 * LDB, BsW + j * 8 * 64);
    bg += 64;
    FENCE();
    // (2) cvt current A regs -> swizzled LDS (compiler waits on their loads)
    {
      u16x8 v;
      v[0] = f2bfu(a0.x); v[1] = f2bfu(a0.y); v[2] = f2bfu(a0.z); v[3] = f2bfu(a0.w);
      v[4] = f2bfu(b0.x); v[5] = f2bfu(b0.y); v[6] = f2bfu(b0.z); v[7] = f2bfu(b0.w);
      *(u16x8*)&As[arow * 64 + slotA] = v;
      v[0] = f2bfu(a1.x); v[1] = f2bfu(a1.y); v[2] = f2bfu(a1.z); v[3] = f2bfu(a1.w);
      v[4] = f2bfu(b1.x); v[5] = f2bfu(b1.y); v[6] = f2bfu(b1.z); v[7] = f2bfu(b1.w);
      *(u16x8*)&As[(32 + arow) * 64 + slotA] = v;
    }
    // (3) issue next-iteration A loads (stay in flight across the barrier);
    //     last iter re-reads the current chunk to keep vmcnt count constant
    //     and stay in-bounds.
    const float* agn = (kt == K / 64 - 1) ? (ag - 64) : ag;
    float4 na0 = ((const float4*)agn)[0];
    float4 nb0 = ((const float4*)agn)[1];
    float4 na1 = ((const float4*)(agn + (size_t)32 * LDA))[0];
    float4 nb1 = ((const float4*)(agn + (size_t)32 * LDA))[1];
    ag += 64;
    FENCE();
    // B DMAs (8) done; A prefetch (4) may remain in flight; LDS writes done.
    asm volatile("s_waitcnt vmcnt(4) lgkmcnt(0)" ::: "memory");
    __builtin_amdgcn_s_barrier();
    FENCE();
    #pragma unroll
    for (int ks = 0; ks < 2; ++ks) {
      s16x8 af[2], bfv[8];
      #pragma unroll
      for (int mi = 0; mi < 2; ++mi) {
        const int row  = waveM * 32 + mi * 16 + l16;
        const int slot = (ks * 4 + quad) ^ xr;
        af[mi] = *(const s16x8*)&As[row * 64 + slot * 8];
      }
      #pragma unroll
      for (int ni = 0; ni < 8; ++ni) {
        const int row  = waveN * 128 + ni * 16 + l16;
        const int slot = (ks * 4 + quad) ^ xr;
        bfv[ni] = *(const s16x8*)&Bs[row * 64 + slot * 8];
      }
      #pragma unroll
      for (int mi = 0; mi < 2; ++mi)
        #pragma unroll
        for (int ni = 0; ni < 8; ++ni)
          acc[mi * 8 + ni] = __builtin_amdgcn_mfma_f32_16x16x32_bf16(
              af[mi], bfv[ni], acc[mi * 8 + ni], 0, 0, 0);
    }
    FENCE();
    asm volatile("s_waitcnt lgkmcnt(0)" ::: "memory");
    __builtin_amdgcn_s_barrier();
    FENCE();
    a0 = na0; b0 = nb0; a1 = na1; b1 = nb1;
  }
}

// z=0: q = (Xq Wq^T + bq) * 512^-0.5 ; z=1: k = Xk Wk^T + bk ;
// z=2: vT[b][d][s] = (Xv Wv^T + bv)^T.
// Flat 768-block grid; the two bn-siblings of each (bm,z) panel get linear
// ids differing by 8 -> same XCD -> A panel shared in that XCD's L2.
__global__ __launch_bounds__(256, 3)
void proj_kernel(const float* __restrict__ Xq, const float* __restrict__ Xk,
                 const float* __restrict__ Xv, const bf16* __restrict__ W0,
                 const float* __restrict__ bq, const float* __restrict__ bk,
                 const float* __restrict__ bv,
                 bf16* __restrict__ qo, bf16* __restrict__ ko,
                 bf16* __restrict__ vT, float qscale)
{
  __shared__ __align__(16) short As[64 * 64];
  __shared__ __align__(16) short Bs[256 * 64];
  const int id   = blockIdx.x;
  const int xcd  = id & 7;
  const int s    = id >> 3;            // 0..95
  const int bn   = s & 1;
  const int pair = (s >> 1) * 8 + xcd; // 0..383 unique
  const int bm   = pair & 127;
  const int z    = pair >> 7;          // 0..2
  const float* A  = (z == 0) ? Xq : (z == 1) ? Xk : Xv;
  const bf16*  Bw = W0 + ((size_t)z << 19);
  const float* bias = (z == 0) ? bq : (z == 1) ? bk : bv;
  f32x4 acc[16];
  gemm_core_f32a<1024, 1024, 1024>(A, Bw, bm, bn, As, Bs, acc);

  const int lane = threadIdx.x & 63;
  const int wave = threadIdx.x >> 6;
  const int waveM = wave >> 1, waveN = wave & 1;
  const int l16 = lane & 15, quad = lane >> 4;
  const int row0 = bm * 64 + waveM * 32;
  const int col0 = bn * 256 + waveN * 128;
  const float sc = (z == 0) ? qscale : 1.0f;
  bf16* C = (z == 0) ? qo : ko;
  #pragma unroll
  for (int ni = 0; ni < 8; ++ni) {
    const int col = col0 + ni * 16 + l16;
    const float bb = bias[col];
    #pragma unroll
    for (int mi = 0; mi < 2; ++mi)
      #pragma unroll
      for (int r = 0; r < 4; ++r) {
        const int row = row0 + mi * 16 + quad * 4 + r;
        const float v = acc[mi * 8 + ni][r] + bb;
        if (z == 2)
          vT[((size_t)(row >> 10) * DKK + col) * SS + (row & (SS - 1))] =
              __float2bfloat16(v);
        else
          C[(size_t)row * DKK + col] = __float2bfloat16(v * sc);
      }
  }
}

// expS[b][s][t] = exp(q[b][s].k[b][t]); 64x128 tiles, minimum-2-phase
// double-buffered pipeline (T3 recipe): STAGE(buf^1, t+1) BEFORE compute
// of buf, single __syncthreads per iter -> the prefetch latency hides under
// the ds_read+MFMA phase instead of sitting naked on the critical path.
// Flat grid 1024: z = id&7 (q+k for one z = 2 MiB, L2-resident per XCD),
// s = id>>3: bm = s&15, bn = s>>4.
__global__ __launch_bounds__(256, 3)
void scores_kernel(const bf16* __restrict__ q, const bf16* __restrict__ k,
                   bf16* __restrict__ lgB)
{
  __shared__ __align__(16) short As[2][64 * 64];
  __shared__ __align__(16) short Bs[2][128 * 64];
  const int id = blockIdx.x;
  const int z  = id & 7;
  const int s  = id >> 3;          // 0..127
  const int bm = s & 15;
  const int bn = s >> 4;           // 0..7
  const bf16* qz = q + (size_t)z * SS * DKK;
  const bf16* kz = k + (size_t)z * SS * DKK;

  const int tid  = threadIdx.x;
  const int lane = tid & 63;
  const int wave = tid >> 6;
  const int l8   = lane >> 3;
  const int kch  = ((lane & 7) ^ l8) * 8;
  const bf16* ag = qz + (size_t)(bm * 64 + wave * 16 + l8) * 512 + kch;
  const bf16* bg = kz + (size_t)(bn * 128 + wave * 32 + l8) * 512 + kch;
  const int asoff = wave * 16 * 64;
  const int bsoff = wave * 32 * 64;
  const int waveM = wave >> 1, waveN = wave & 1;
  const int l16  = lane & 15;
  const int quad = lane >> 4;
  const int xr   = l16 & 7;

  f32x4 acc[8];
  #pragma unroll
  for (int t = 0; t < 8; ++t)
    #pragma unroll
    for (int r = 0; r < 4; ++r) acc[t][r] = 0.0f;

  // prologue: stage tile 0 into buffer 0
  #pragma unroll
  for (int j = 0; j < 2; ++j) async_ld16(ag + (size_t)j * 8 * 512, &As[0][asoff + j * 8 * 64]);
  #pragma unroll
  for (int j = 0; j < 4; ++j) async_ld16(bg + (size_t)j * 8 * 512, &Bs[0][bsoff + j * 8 * 64]);
  ag += 64; bg += 64;
  __syncthreads();

  for (int kt = 0; kt < 8; ++kt) {
    const int cur = kt & 1;
    if (kt < 7) {
      #pragma unroll
      for (int j = 0; j < 2; ++j) async_ld16(ag + (size_t)j * 8 * 512, &As[cur ^ 1][asoff + j * 8 * 64]);
      #pragma unroll
      for (int j = 0; j < 4; ++j) async_ld16(bg + (size_t)j * 8 * 512, &Bs[cur ^ 1][bsoff + j * 8 * 64]);
      ag += 64; bg += 64;
    }
    __builtin_amdgcn_s_setprio(1);
    #pragma unroll
    for (int ks = 0; ks < 2; ++ks) {
      s16x8 af[2], bfv[4];
      #pragma unroll
      for (int mi = 0; mi < 2; ++mi) {
        const int row  = waveM * 32 + mi * 16 + l16;
        const int slot = (ks * 4 + quad) ^ xr;
        af[mi] = *(const s16x8*)&As[cur][row * 64 + slot * 8];
      }
      #pragma unroll
      for (int ni = 0; ni < 4; ++ni) {
        const int row  = waveN * 64 + ni * 16 + l16;
        const int slot = (ks * 4 + quad) ^ xr;
        bfv[ni] = *(const s16x8*)&Bs[cur][row * 64 + slot * 8];
      }
      #pragma unroll
      for (int mi = 0; mi < 2; ++mi)
        #pragma unroll
        for (int ni = 0; ni < 4; ++ni)
          acc[mi * 4 + ni] = __builtin_amdgcn_mfma_f32_16x16x32_bf16(
              af[mi], bfv[ni], acc[mi * 4 + ni], 0, 0, 0);
    }
    __builtin_amdgcn_s_setprio(0);
    __syncthreads();   // drains the in-flight prefetch -> buf[cur^1] ready
  }

  const int row0 = bm * 64 + waveM * 32;
  const int col0 = bn * 128 + waveN * 64;
  bf16* C = lgB + (size_t)z * SS * SS;
  #pragma unroll
  for (int ni = 0; ni < 4; ++ni) {
    const int col = col0 + ni * 16 + l16;
    #pragma unroll
    for (int mi = 0; mi < 2; ++mi)
      #pragma unroll
      for (int r = 0; r < 4; ++r) {
        const int row = row0 + mi * 16 + quad * 4 + r;
        C[(size_t)row * SS + col] = __float2bfloat16(__expf(acc[mi * 4 + ni][r]));
      }
  }
}

// out[b][s][d] = (P . vT) / rowsum(P), P = expS bf16; f32 out.
// Minimum-2-phase double-buffered all-DMA GEMM (same schedule as scores).
// The denominator is accumulated during the MFMA phase: the 4 quad-lanes of
// each row read that row's full 64-wide k-slice per iteration (slot XOR is a
// bijection), so summing af fragments per lane + shfl_xor(16|32) at the end
// gives exact row sums of the bf16 P values fed to the MFMA.
// Flat grid 512 (2/CU): z = id&7, s = id>>3: bm = s&15, bn = s>>4 (0..3).
__global__ __launch_bounds__(256, 3)
void pv_kernel(const bf16* __restrict__ P, const bf16* __restrict__ vT,
               float* __restrict__ out)
{
  __shared__ __align__(16) short As[2][64 * 64];
  __shared__ __align__(16) short Bs[2][128 * 64];
  __shared__ float Ls[64];
  const int id = blockIdx.x;
  const int z  = id & 7;
  const int sx = id >> 3;          // 0..63
  const int bm = sx & 15;
  const int bn = sx >> 4;          // 0..3
  const bf16* A  = P  + (size_t)z * SS * SS;
  const bf16* Bw = vT + (size_t)z * DKK * SS;

  const int tid  = threadIdx.x;
  const int lane = tid & 63;
  const int wave = tid >> 6;
  const int l8   = lane >> 3;
  const int kch  = ((lane & 7) ^ l8) * 8;
  const bf16* ag = A  + (size_t)(bm * 64 + wave * 16 + l8) * 1024 + kch;
  const bf16* bg = Bw + (size_t)(bn * 128 + wave * 32 + l8) * 1024 + kch;
  const int asoff = wave * 16 * 64;
  const int bsoff = wave * 32 * 64;
  const int waveM = wave >> 1, waveN = wave & 1;
  const int l16  = lane & 15;
  const int quad = lane >> 4;
  const int xr   = l16 & 7;

  f32x4 acc[8];
  #pragma unroll
  for (int t = 0; t < 8; ++t)
    #pragma unroll
    for (int r = 0; r < 4; ++r) acc[t][r] = 0.0f;
  float es0 = 0.0f, es1 = 0.0f;   // row sums for rows waveM*32 + {l16, 16+l16}

  // prologue: stage tile 0 into buffer 0
  #pragma unroll
  for (int j = 0; j < 2; ++j) async_ld16(ag + (size_t)j * 8 * 1024, &As[0][asoff + j * 8 * 64]);
  #pragma unroll
  for (int j = 0; j < 4; ++j) async_ld16(bg + (size_t)j * 8 * 1024, &Bs[0][bsoff + j * 8 * 64]);
  ag += 64; bg += 64;
  __syncthreads();

  for (int kt = 0; kt < 16; ++kt) {
    const int cur = kt & 1;
    if (kt < 15) {
      #pragma unroll
      for (int j = 0; j < 2; ++j) async_ld16(ag + (size_t)j * 8 * 1024, &As[cur ^ 1][asoff + j * 8 * 64]);
      #pragma unroll
      for (int j = 0; j < 4; ++j) async_ld16(bg + (size_t)j * 8 * 1024, &Bs[cur ^ 1][bsoff + j * 8 * 64]);
      ag += 64; bg += 64;
    }
    __builtin_amdgcn_s_setprio(1);
    #pragma unroll
    for (int ks = 0; ks < 2; ++ks) {
      s16x8 af[2], bfv[4];
      #pragma unroll
      for (int mi = 0; mi < 2; ++mi) {
        const int row  = waveM * 32 + mi * 16 + l16;
        const int slot = (ks * 4 + quad) ^ xr;
        af[mi] = *(const s16x8*)&As[cur][row * 64 + slot * 8];
      }
      // denominator accumulation from the same fragments (VALU, co-issues
      // with the MFMA pipe)
      {
        const u16x8 u0 = __builtin_bit_cast(u16x8, af[0]);
        const u16x8 u1 = __builtin_bit_cast(u16x8, af[1]);
        #pragma unroll
        for (int e = 0; e < 8; ++e) {
          es0 += bfu2f((unsigned short)u0[e]);
          es1 += bfu2f((unsigned short)u1[e]);
        }
      }
      #pragma unroll
      for (int ni = 0; ni < 4; ++ni) {
        const int row  = waveN * 64 + ni * 16 + l16;
        const int slot = (ks * 4 + quad) ^ xr;
        bfv[ni] = *(const s16x8*)&Bs[cur][row * 64 + slot * 8];
      }
      #pragma unroll
      for (int mi = 0; mi < 2; ++mi)
        #pragma unroll
        for (int ni = 0; ni < 4; ++ni)
          acc[mi * 4 + ni] = __builtin_amdgcn_mfma_f32_16x16x32_bf16(
              af[mi], bfv[ni], acc[mi * 4 + ni], 0, 0, 0);
    }
    __builtin_amdgcn_s_setprio(0);
    __syncthreads();   // drains the in-flight prefetch -> buf[cur^1] ready
  }

  // combine across the 4 quad-lanes of each row (lanes differ in bits 4,5)
  es0 += __shfl_xor(es0, 16); es0 += __shfl_xor(es0, 32);
  es1 += __shfl_xor(es1, 16); es1 += __shfl_xor(es1, 32);
  if (waveN == 0 && quad == 0) {
    Ls[waveM * 32 + l16]      = 1.0f / es0;
    Ls[waveM * 32 + 16 + l16] = 1.0f / es1;
  }
  __syncthreads();

  const int col0 = bn * 128 + waveN * 64;
  float* C = out + (size_t)z * SS * DKK;
  #pragma unroll
  for (int mi = 0; mi < 2; ++mi)
    #pragma unroll
    for (int r = 0; r < 4; ++r) {
      const int rl  = waveM * 32 + mi * 16 + quad * 4 + r;
      const float inv = Ls[rl];
      const int row = bm * 64 + rl;
      #pragma unroll
      for (int ni = 0; ni < 4; ++ni) {
        const int col = col0 + ni * 16 + l16;
        C[(size_t)row * DKK + col] = acc[mi * 4 + ni][r] * inv;
      }
    }
}

extern "C" void kernel_launch(void* const* d_in, const int* in_sizes, int n_in,
                              void* d_out, int out_size, void* d_ws, size_t ws_size,
                              hipStream_t stream)
{
  char* ws = (char*)d_ws;
  bf16*  W0   = (bf16*)(ws + WS_W(0));
  bf16*  q    = (bf16*)(ws + WS_Q);
  bf16*  kk   = (bf16*)(ws + WS_K);
  bf16*  vT   = (bf16*)(ws + WS_VT);
  bf16*  lgB  = (bf16*)(ws + WS_LG);

  const float qscale = 0.044194173824159216f;  // 512^-0.5

  dim3 blk(256, 1, 1);
  // d_in order: qin,kin,vin,Wq,bq,Wk,bk,Wv,bv (all f32)
  hipLaunchKernelGGL(convert_w, dim3(768), blk, 0, stream,
                     (const float*)d_in[3], (const float*)d_in[5],
                     (const float*)d_in[7], ws);
  hipLaunchKernelGGL(proj_kernel, dim3(768, 1, 1), blk, 0, stream,
                     (const float*)d_in[0], (const float*)d_in[1],
                     (const float*)d_in[2], W0,
                     (const float*)d_in[4], (const float*)d_in[6],
                     (const float*)d_in[8], q, kk, vT, qscale);
  hipLaunchKernelGGL(scores_kernel, dim3(1024, 1, 1), blk, 0, stream,
                     q, kk, lgB);
  hipLaunchKernelGGL(pv_kernel, dim3(512, 1, 1), blk, 0, stream,
                     lgB, vT, (float*)d_out);
}